// Round 3
// baseline (277.874 us; speedup 1.0000x reference)
//
#include <hip/hip_runtime.h>

// QuantizedWeight dequant:
//   out[g*8+j] = (cb[0, codes[g,0], j] + cb[1, codes[g,1], j]) * scales[g] + zeros[g]
// codes (8192*1024, 2) i32, codebooks (2,65536,8) f32, scales/zeros (8192*1024) f32,
// out = 8192*8192 f32 flat; group g writes out[8g..8g+8).
//
// Thread granularity: one PAIR of consecutive groups per thread:
//   codes  -> one int4   (2 groups' 2 codes each)
//   scales -> one float2, zeros -> one float2
//   output -> 64 B contiguous per thread (one full line per lane)
// 2x unroll (two pair-chunks per grid-stride iteration), all gathers batched
// before any consume for memory-level parallelism.
// Streams use nontemporal (evict-first) so the 4 MB codebook stays L2-resident.

typedef float vf4 __attribute__((ext_vector_type(4)));
typedef float vf2 __attribute__((ext_vector_type(2)));
typedef int   vi4 __attribute__((ext_vector_type(4)));

__global__ __launch_bounds__(256) void
dequant_kernel(const int* __restrict__ codes,
               const float* __restrict__ cbs,      // [2][65536][8]
               const float* __restrict__ scales,
               const float* __restrict__ zeros,
               float* __restrict__ out,
               int total_pairs)                     // = 8192*1024/2
{
    const size_t CB1 = (size_t)65536 * 8;           // codebook 1 base (floats)
    const int stride = gridDim.x * blockDim.x;
    const vi4* codes4  = (const vi4*)codes;
    const vf2* scales2 = (const vf2*)scales;
    const vf2* zeros2  = (const vf2*)zeros;
    vf4* out4 = (vf4*)out;

    int p = blockIdx.x * blockDim.x + threadIdx.x;

    // main loop: 2 pair-chunks (4 groups) per iteration
    for (; p + stride < total_pairs; p += 2 * stride) {
        const int pA = p;
        const int pB = p + stride;

        // ---- streaming loads (nt), both chunks up front ----
        vi4 cA = __builtin_nontemporal_load(codes4 + pA);
        vi4 cB = __builtin_nontemporal_load(codes4 + pB);
        vf2 sA = __builtin_nontemporal_load(scales2 + pA);
        vf2 sB = __builtin_nontemporal_load(scales2 + pB);
        vf2 zA = __builtin_nontemporal_load(zeros2 + pA);
        vf2 zB = __builtin_nontemporal_load(zeros2 + pB);

        // ---- 16 independent gathers (cached; codebook L2-resident) ----
        const vf4* a0 = (const vf4*)(cbs + (size_t)cA.x * 8);
        const vf4* a1 = (const vf4*)(cbs + CB1 + (size_t)cA.y * 8);
        const vf4* a2 = (const vf4*)(cbs + (size_t)cA.z * 8);
        const vf4* a3 = (const vf4*)(cbs + CB1 + (size_t)cA.w * 8);
        const vf4* b0 = (const vf4*)(cbs + (size_t)cB.x * 8);
        const vf4* b1 = (const vf4*)(cbs + CB1 + (size_t)cB.y * 8);
        const vf4* b2 = (const vf4*)(cbs + (size_t)cB.z * 8);
        const vf4* b3 = (const vf4*)(cbs + CB1 + (size_t)cB.w * 8);

        vf4 a0l = a0[0], a0h = a0[1], a1l = a1[0], a1h = a1[1];
        vf4 a2l = a2[0], a2h = a2[1], a3l = a3[0], a3h = a3[1];
        vf4 b0l = b0[0], b0h = b0[1], b1l = b1[0], b1h = b1[1];
        vf4 b2l = b2[0], b2h = b2[1], b3l = b3[0], b3h = b3[1];

        // ---- compute + store chunk A (64 B contiguous per thread) ----
        vf4 rA0 = (a0l + a1l) * sA.x + zA.x;
        vf4 rA1 = (a0h + a1h) * sA.x + zA.x;
        vf4 rA2 = (a2l + a3l) * sA.y + zA.y;
        vf4 rA3 = (a2h + a3h) * sA.y + zA.y;
        __builtin_nontemporal_store(rA0, out4 + (size_t)4 * pA);
        __builtin_nontemporal_store(rA1, out4 + (size_t)4 * pA + 1);
        __builtin_nontemporal_store(rA2, out4 + (size_t)4 * pA + 2);
        __builtin_nontemporal_store(rA3, out4 + (size_t)4 * pA + 3);

        // ---- compute + store chunk B ----
        vf4 rB0 = (b0l + b1l) * sB.x + zB.x;
        vf4 rB1 = (b0h + b1h) * sB.x + zB.x;
        vf4 rB2 = (b2l + b3l) * sB.y + zB.y;
        vf4 rB3 = (b2h + b3h) * sB.y + zB.y;
        __builtin_nontemporal_store(rB0, out4 + (size_t)4 * pB);
        __builtin_nontemporal_store(rB1, out4 + (size_t)4 * pB + 1);
        __builtin_nontemporal_store(rB2, out4 + (size_t)4 * pB + 2);
        __builtin_nontemporal_store(rB3, out4 + (size_t)4 * pB + 3);
    }

    // tail: single pair per iteration
    for (; p < total_pairs; p += stride) {
        vi4 c = __builtin_nontemporal_load(codes4 + p);
        vf2 s = __builtin_nontemporal_load(scales2 + p);
        vf2 z = __builtin_nontemporal_load(zeros2 + p);
        const vf4* e0 = (const vf4*)(cbs + (size_t)c.x * 8);
        const vf4* e1 = (const vf4*)(cbs + CB1 + (size_t)c.y * 8);
        const vf4* e2 = (const vf4*)(cbs + (size_t)c.z * 8);
        const vf4* e3 = (const vf4*)(cbs + CB1 + (size_t)c.w * 8);
        vf4 e0l = e0[0], e0h = e0[1], e1l = e1[0], e1h = e1[1];
        vf4 e2l = e2[0], e2h = e2[1], e3l = e3[0], e3h = e3[1];
        vf4 r0 = (e0l + e1l) * s.x + z.x;
        vf4 r1 = (e0h + e1h) * s.x + z.x;
        vf4 r2 = (e2l + e3l) * s.y + z.y;
        vf4 r3 = (e2h + e3h) * s.y + z.y;
        __builtin_nontemporal_store(r0, out4 + (size_t)4 * p);
        __builtin_nontemporal_store(r1, out4 + (size_t)4 * p + 1);
        __builtin_nontemporal_store(r2, out4 + (size_t)4 * p + 2);
        __builtin_nontemporal_store(r3, out4 + (size_t)4 * p + 3);
    }
}

extern "C" void kernel_launch(void* const* d_in, const int* in_sizes, int n_in,
                              void* d_out, int out_size, void* d_ws, size_t ws_size,
                              hipStream_t stream) {
    const int*   codes     = (const int*)  d_in[0];
    const float* codebooks = (const float*)d_in[1];
    const float* scales    = (const float*)d_in[2];
    const float* zeros     = (const float*)d_in[3];
    float*       out       = (float*)d_out;

    const int total_pairs = in_sizes[0] / 4;  // groups/2

    const int threads = 256;
    int blocks = (total_pairs + threads - 1) / threads;
    if (blocks > 2048) blocks = 2048;   // grid-stride; full wave residency

    dequant_kernel<<<blocks, threads, 0, stream>>>(
        codes, codebooks, scales, zeros, out, total_pairs);
}

// Round 4
// 186.673 us; speedup vs baseline: 1.4886x; 1.4886x over previous
//
#include <hip/hip_runtime.h>

// QuantizedWeight dequant:
//   out[g*8+j] = (cb[0, codes[g,0], j] + cb[1, codes[g,1], j]) * scales[g] + zeros[g]
// codes (8.4M, 2) i32, codebooks (2,65536,8) f32, scales/zeros (8.4M) f32,
// out flat 8192*8192 f32; group g owns out[8g..8g+8).
//
// Two lanes per group: lane pair (2k,2k+1) shares group g = tid>>1; each lane
// handles the (tid&1)-th 16 B half of both codebook entries and of the output.
//   - gather: pair lanes hit the SAME 64 B line (entry is 32 B, line-aligned
//     within its 64 B line) -> <=32 line-requests per instruction, 2 per group
//     (the minimum), vs 4 with one-group-per-lane.
//   - store: addr = out + g*32B + (tid&1)*16 -> 16 B/lane fully contiguous
//     across the wave = full-line-dense nt stores (no write amplification).
// Streams (codes/scales/zeros) stay nontemporal so the 4 MB codebook remains
// L2-resident; gathers use cached loads. 2x unroll batches 4 gathers for MLP.

typedef float vf4 __attribute__((ext_vector_type(4)));
typedef int   vi2 __attribute__((ext_vector_type(2)));

__global__ __launch_bounds__(256) void
dequant_kernel(const int* __restrict__ codes,
               const float* __restrict__ cbs,      // [2][65536][8]
               const float* __restrict__ scales,
               const float* __restrict__ zeros,
               float* __restrict__ out,
               int total)                           // groups = 8192*1024
{
    const size_t CB1 = (size_t)65536 * 8;           // codebook 1 base (floats)
    const vi2* codes2 = (const vi2*)codes;

    const int tid    = blockIdx.x * blockDim.x + threadIdx.x;
    const int half   = tid & 1;                     // which 16 B half
    const int gstep  = (gridDim.x * blockDim.x) >> 1;
    const int hoff   = half * 4;                    // float offset of my half

    int g = tid >> 1;

    // main loop: 2 groups per lane-pair per iteration (gathers batched)
    for (; g + gstep < total; g += 2 * gstep) {
        const int gA = g;
        const int gB = g + gstep;

        // streaming loads (nt) — pair lanes duplicate-load same addr (coalesces)
        vi2  cA = __builtin_nontemporal_load(codes2 + gA);
        vi2  cB = __builtin_nontemporal_load(codes2 + gB);
        float sA = __builtin_nontemporal_load(scales + gA);
        float sB = __builtin_nontemporal_load(scales + gB);
        float zA = __builtin_nontemporal_load(zeros + gA);
        float zB = __builtin_nontemporal_load(zeros + gB);

        // 4 independent gathers; pair lanes hit the same 64 B line
        vf4 eA0 = *(const vf4*)(cbs + (size_t)cA.x * 8 + hoff);
        vf4 eA1 = *(const vf4*)(cbs + CB1 + (size_t)cA.y * 8 + hoff);
        vf4 eB0 = *(const vf4*)(cbs + (size_t)cB.x * 8 + hoff);
        vf4 eB1 = *(const vf4*)(cbs + CB1 + (size_t)cB.y * 8 + hoff);

        vf4 rA = (eA0 + eA1) * sA + zA;
        vf4 rB = (eB0 + eB1) * sB + zB;

        // dense nt stores: 16 B/lane contiguous across the wave
        __builtin_nontemporal_store(rA, (vf4*)(out + (size_t)gA * 8 + hoff));
        __builtin_nontemporal_store(rB, (vf4*)(out + (size_t)gB * 8 + hoff));
    }

    // tail
    for (; g < total; g += gstep) {
        vi2  c = __builtin_nontemporal_load(codes2 + g);
        float s = __builtin_nontemporal_load(scales + g);
        float z = __builtin_nontemporal_load(zeros + g);
        vf4 e0 = *(const vf4*)(cbs + (size_t)c.x * 8 + hoff);
        vf4 e1 = *(const vf4*)(cbs + CB1 + (size_t)c.y * 8 + hoff);
        vf4 r = (e0 + e1) * s + z;
        __builtin_nontemporal_store(r, (vf4*)(out + (size_t)g * 8 + hoff));
    }
}

extern "C" void kernel_launch(void* const* d_in, const int* in_sizes, int n_in,
                              void* d_out, int out_size, void* d_ws, size_t ws_size,
                              hipStream_t stream) {
    const int*   codes     = (const int*)  d_in[0];
    const float* codebooks = (const float*)d_in[1];
    const float* scales    = (const float*)d_in[2];
    const float* zeros     = (const float*)d_in[3];
    float*       out       = (float*)d_out;

    const int total = in_sizes[0] / 2;   // number of groups

    const int threads = 256;
    int blocks = 2048;                   // 524288 threads = 262144 lane-pairs
    dequant_kernel<<<blocks, threads, 0, stream>>>(
        codes, codebooks, scales, zeros, out, total);
}

// Round 5
// 160.127 us; speedup vs baseline: 1.7353x; 1.1658x over previous
//
#include <hip/hip_runtime.h>

// QuantizedWeight dequant:
//   out[g*8+j] = (cb[0, codes[g,0], j] + cb[1, codes[g,1], j]) * scales[g] + zeros[g]
// codes (8.4M,2) i32, codebooks (2,65536,8) f32, scales/zeros (8.4M) f32,
// out flat 8192*8192 f32.
//
// r5: wave-cooperative LDS staging to kill duplicated stream lane-requests.
// Each wave owns 128 consecutive groups per super-iteration:
//   stream phase (3 dense wide loads/lane):
//     lane l: codes int4  (groups 2l,2l+1)  -> 1 KB/wave
//             scales float2, zeros float2   -> packed as {s0,z0,s1,z1} float4
//   stage into per-wave 2 KB LDS region (wave-synchronous, no __syncthreads)
//   4 sub-iters, pair geometry (proven in r4):
//     pair p owns group q=32k+p; both lanes ds_read_b64 codes[q] + sz[q]
//     (same-addr broadcast, conflict-free), gather their 16B half of each
//     entry (pair lanes share the 64B line), dense 16B/lane nt store.
// Streams/stores nontemporal (codebook stays L2-resident; WRITE=ideal proven).
// VMEM lane-ops/group: 12 (r4) -> 7.5.

typedef float vf4 __attribute__((ext_vector_type(4)));
typedef float vf2 __attribute__((ext_vector_type(2)));
typedef int   vi4 __attribute__((ext_vector_type(4)));
typedef int   vi2 __attribute__((ext_vector_type(2)));

__global__ __launch_bounds__(256) void
dequant_kernel(const int* __restrict__ codes,
               const float* __restrict__ cbs,      // [2][65536][8]
               const float* __restrict__ scales,
               const float* __restrict__ zeros,
               float* __restrict__ out,
               int total)                           // groups
{
    const size_t CB1 = (size_t)65536 * 8;           // codebook 1 base (floats)

    __shared__ __align__(16) char lds_raw[4 * 2048];
    const int lane = threadIdx.x & 63;
    const int wid  = threadIdx.x >> 6;
    char* wlds = lds_raw + wid * 2048;              // [0,1024): codes[128][2]
                                                    // [1024,2048): {s,z}[128]

    const int  nwaves = (gridDim.x * blockDim.x) >> 6;
    const int  wave   = (blockIdx.x * blockDim.x + threadIdx.x) >> 6;
    const long wstep  = (long)nwaves * 128;

    const vi4* codes4  = (const vi4*)codes;
    const vf2* scales2 = (const vf2*)scales;
    const vf2* zeros2  = (const vf2*)zeros;

    const int half = lane & 1;                      // which 16B half of entries
    const int hoff = half * 4;                      // float offset
    const int pidx = lane >> 1;                     // pair index 0..31

    long gbase = (long)wave * 128;

    if (gbase + 128 <= total) {
        // prologue: issue stream loads for first super-iteration
        long sidx = (gbase >> 1) + lane;
        vi4 pc = __builtin_nontemporal_load(codes4 + sidx);
        vf2 ps = __builtin_nontemporal_load(scales2 + sidx);
        vf2 pz = __builtin_nontemporal_load(zeros2 + sidx);

        for (;;) {
            const long gcur = gbase;
            gbase += wstep;
            const bool more = (gbase + 128 <= total);

            // stage current super-iteration into LDS (wave-synchronous)
            *(vi4*)(wlds + lane * 16) = pc;
            vf4 szv; szv.x = ps.x; szv.y = pz.x; szv.z = ps.y; szv.w = pz.y;
            *(vf4*)(wlds + 1024 + lane * 16) = szv;

            // prefetch next super-iteration's streams (lands during compute)
            if (more) {
                long nidx = (gbase >> 1) + lane;
                pc = __builtin_nontemporal_load(codes4 + nidx);
                ps = __builtin_nontemporal_load(scales2 + nidx);
                pz = __builtin_nontemporal_load(zeros2 + nidx);
            }

            // 4 sub-iterations x 32 groups, r4 pair geometry
            #pragma unroll
            for (int k = 0; k < 4; ++k) {
                const int q = k * 32 + pidx;
                vi2 c  = *(const vi2*)(wlds + q * 8);        // broadcast read
                vf2 sz = *(const vf2*)(wlds + 1024 + q * 8); // broadcast read
                vf4 e0 = *(const vf4*)(cbs + (size_t)c.x * 8 + hoff);
                vf4 e1 = *(const vf4*)(cbs + CB1 + (size_t)c.y * 8 + hoff);
                vf4 r  = (e0 + e1) * sz.x + sz.y;
                __builtin_nontemporal_store(
                    r, (vf4*)(out + (size_t)(gcur + q) * 8 + hoff));
            }
            if (!more) break;
        }
    }

    // tail: groups not covered by full 128-blocks (none at 8.39M, kept for safety)
    const long total_full = ((long)total >> 7) << 7;
    const int  gtid  = blockIdx.x * blockDim.x + threadIdx.x;
    const long pstep = (long)(gridDim.x * blockDim.x) >> 1;
    for (long g = total_full + (gtid >> 1); g < total; g += pstep) {
        vi2  c = *(const vi2*)(codes + (size_t)2 * g);
        float s = scales[g];
        float z = zeros[g];
        vf4 e0 = *(const vf4*)(cbs + (size_t)c.x * 8 + hoff);
        vf4 e1 = *(const vf4*)(cbs + CB1 + (size_t)c.y * 8 + hoff);
        vf4 r  = (e0 + e1) * s + z;
        __builtin_nontemporal_store(r, (vf4*)(out + (size_t)g * 8 + hoff));
    }
}

extern "C" void kernel_launch(void* const* d_in, const int* in_sizes, int n_in,
                              void* d_out, int out_size, void* d_ws, size_t ws_size,
                              hipStream_t stream) {
    const int*   codes     = (const int*)  d_in[0];
    const float* codebooks = (const float*)d_in[1];
    const float* scales    = (const float*)d_in[2];
    const float* zeros     = (const float*)d_in[3];
    float*       out       = (float*)d_out;

    const int total = in_sizes[0] / 2;   // number of groups

    const int threads = 256;
    const int blocks  = 2048;            // 8192 waves x 1024 groups = 8.39M exact
    dequant_kernel<<<blocks, threads, 0, stream>>>(
        codes, codebooks, scales, zeros, out, total);
}